// Round 1
// baseline (11509.048 us; speedup 1.0000x reference)
//
#include <hip/hip_runtime.h>
#include <hip/hip_bf16.h>

#define NATTRS 200
#define NOBJS  500
#define NNODE  700
#define IN_F   512
#define HID    2048
#define NODE_D 512
#define IMG_D  512
#define EMB    800
#define BB     256
#define P_H1   1000
#define NPAIR  100000

// ---------------- async global->LDS (16B) ----------------
typedef const __attribute__((address_space(1))) unsigned int* gas_ptr;
typedef __attribute__((address_space(3))) unsigned int* las_ptr;
__device__ __forceinline__ void async_copy16(float* lds, const float* g) {
  __builtin_amdgcn_global_load_lds((gas_ptr)(const void*)g, (las_ptr)(void*)lds, 16, 0, 0);
}

// ---------------- CSR build ----------------
__global__ void k_count(const int* __restrict__ ei, int* __restrict__ cnt, int E) {
  int e = blockIdx.x * 256 + threadIdx.x;
  if (e < E) atomicAdd(&cnt[ei[E + e]], 1);
}

__global__ __launch_bounds__(1024) void k_scan(const int* __restrict__ cnt,
                                               int* __restrict__ row_start,
                                               int* __restrict__ pos) {
  __shared__ int s[1024];
  int t = threadIdx.x;
  int my = (t < NNODE) ? cnt[t] : 0;
  s[t] = my;
  __syncthreads();
  for (int off = 1; off < 1024; off <<= 1) {
    int add = (t >= off) ? s[t - off] : 0;
    __syncthreads();
    s[t] += add;
    __syncthreads();
  }
  int excl = s[t] - my;
  if (t < NNODE) { row_start[t] = excl; pos[t] = excl; }
  if (t == 0) row_start[NNODE] = s[1023];
}

__global__ void k_fill(const int* __restrict__ ei, int* __restrict__ pos,
                       int* __restrict__ srcs, int E) {
  int e = blockIdx.x * 256 + threadIdx.x;
  if (e < E) {
    int d = ei[E + e];
    int idx = atomicAdd(&pos[d], 1);
    srcs[idx] = ei[e];
  }
}

// mean aggregation: out[n][d] = sum_{e in row(n)} X[srcs[e]][d] / max(deg,1)
__global__ __launch_bounds__(256) void agg_mean(const float* __restrict__ X,
                                                const int* __restrict__ srcs,
                                                const int* __restrict__ row_start,
                                                float* __restrict__ outp, int D) {
  int node = blockIdx.x;
  int d = blockIdx.y * 256 + threadIdx.x;
  int e0 = row_start[node], e1 = row_start[node + 1];
  float s = 0.f;
  for (int e = e0; e < e1; ++e) s += X[srcs[e] * D + d];
  float c = (float)(e1 - e0);
  outp[node * D + d] = s / fmaxf(c, 1.f);
}

// ---------------- generic small GEMM: C = act(A@B (+A2@B2) + bias) ----------------
template <int ACT, bool HAS2, bool HASB>
__global__ __launch_bounds__(256) void gemm_f32(const float* __restrict__ A,
                                                const float* __restrict__ B,
                                                const float* __restrict__ A2,
                                                const float* __restrict__ B2,
                                                const float* __restrict__ bias,
                                                float* __restrict__ C,
                                                int M, int N, int K) {
  __shared__ float As[16][68];
  __shared__ float Bs[16][64];
  const int n0 = blockIdx.x * 64, m0 = blockIdx.y * 64;
  const int tid = threadIdx.x;
  const int ty = tid >> 4, tx = tid & 15;
  float acc[4][4] = {};
  const int npass = HAS2 ? 2 : 1;
  for (int pass = 0; pass < npass; ++pass) {
    const float* Ap = (HAS2 && pass) ? A2 : A;
    const float* Bp = (HAS2 && pass) ? B2 : B;
    for (int k0 = 0; k0 < K; k0 += 16) {
      __syncthreads();
      #pragma unroll
      for (int ii = 0; ii < 4; ++ii) {
        int idx = tid + 256 * ii;
        int m = idx >> 4, k = idx & 15;
        float v = 0.f;
        if (m0 + m < M && k0 + k < K) v = Ap[(m0 + m) * K + k0 + k];
        As[k][m] = v;
      }
      #pragma unroll
      for (int ii = 0; ii < 4; ++ii) {
        int idx = tid + 256 * ii;
        int k = idx >> 6, n = idx & 63;
        float v = 0.f;
        if (k0 + k < K && n0 + n < N) v = Bp[(k0 + k) * N + n0 + n];
        Bs[k][n] = v;
      }
      __syncthreads();
      #pragma unroll
      for (int kk = 0; kk < 16; ++kk) {
        const float4 a4 = *(const float4*)&As[kk][4 * ty];
        const float4 b4 = *(const float4*)&Bs[kk][4 * tx];
        acc[0][0] += a4.x * b4.x; acc[0][1] += a4.x * b4.y; acc[0][2] += a4.x * b4.z; acc[0][3] += a4.x * b4.w;
        acc[1][0] += a4.y * b4.x; acc[1][1] += a4.y * b4.y; acc[1][2] += a4.y * b4.z; acc[1][3] += a4.y * b4.w;
        acc[2][0] += a4.z * b4.x; acc[2][1] += a4.z * b4.y; acc[2][2] += a4.z * b4.z; acc[2][3] += a4.z * b4.w;
        acc[3][0] += a4.w * b4.x; acc[3][1] += a4.w * b4.y; acc[3][2] += a4.w * b4.z; acc[3][3] += a4.w * b4.w;
      }
    }
  }
  #pragma unroll
  for (int i = 0; i < 4; ++i) {
    int m = m0 + 4 * ty + i;
    if (m >= M) continue;
    #pragma unroll
    for (int j = 0; j < 4; ++j) {
      int n = n0 + 4 * tx + j;
      if (n >= N) continue;
      float v = acc[i][j];
      if (HASB) v += bias[n];
      if (ACT == 1) v = fmaxf(v, 0.f);
      C[m * N + n] = v;
    }
  }
}

// ---------------- row LayerNorm (in-place), optional relu ----------------
template <bool RELU>
__global__ __launch_bounds__(256) void ln_rows(float* __restrict__ X,
                                               const float* __restrict__ g,
                                               const float* __restrict__ b, int N) {
  int row = blockIdx.x, tid = threadIdx.x;
  float* x = X + row * N;
  float s1 = 0.f, s2 = 0.f;
  for (int i = tid; i < N; i += 256) { float v = x[i]; s1 += v; s2 += v * v; }
  #pragma unroll
  for (int m = 1; m < 64; m <<= 1) { s1 += __shfl_xor(s1, m); s2 += __shfl_xor(s2, m); }
  __shared__ float r1[4], r2[4];
  int wv = tid >> 6;
  if ((tid & 63) == 0) { r1[wv] = s1; r2[wv] = s2; }
  __syncthreads();
  s1 = r1[0] + r1[1] + r1[2] + r1[3];
  s2 = r2[0] + r2[1] + r2[2] + r2[3];
  float inv = 1.f / (float)N;
  float mu = s1 * inv;
  float rstd = rsqrtf(s2 * inv - mu * mu + 1e-5f);
  for (int i = tid; i < N; i += 256) {
    float v = (x[i] - mu) * rstd * g[i] + b[i];
    if (RELU) v = fmaxf(v, 0.f);
    x[i] = v;
  }
}

// ---------------- img_feats transpose [256][800] -> [800][256] ----------------
__global__ void transpose_img(const float* __restrict__ X, float* __restrict__ Y) {
  int n = blockIdx.x, b = threadIdx.x;
  Y[n * BB + b] = X[b * EMB + n];
}

// ---------------- per-pair LN1 stats: x = B1[a] + O1[o] ----------------
__global__ __launch_bounds__(256) void pair_stats(const float* __restrict__ B1v,
                                                  const float* __restrict__ O1v,
                                                  float* __restrict__ meanp,
                                                  float* __restrict__ rstdp) {
  int pair = blockIdx.x * 4 + (threadIdx.x >> 6);
  int l = threadIdx.x & 63;
  int a = pair / 500, o = pair - a * 500;
  const float* br = B1v + a * P_H1;
  const float* orw = O1v + o * P_H1;
  float s1 = 0.f, s2 = 0.f;
  for (int k = l; k < P_H1; k += 64) { float v = br[k] + orw[k]; s1 += v; s2 += v * v; }
  #pragma unroll
  for (int m = 1; m < 64; m <<= 1) { s1 += __shfl_xor(s1, m); s2 += __shfl_xor(s2, m); }
  if (l == 0) {
    float mu = s1 * (1.f / P_H1);
    meanp[pair] = mu;
    rstdp[pair] = rsqrtf(s2 * (1.f / P_H1) - mu * mu + 1e-5f);
  }
}

// ---------------- fused pair mega-kernel ----------------
// per block: 1 attr x 32 objs. GEMM2 (u@W2, u regenerated on the fly) -> LN2 -> GEMM3 (img_feats @ v^T)
__global__ __launch_bounds__(256) void pair_mega(
    const float* __restrict__ B1v, const float* __restrict__ O1v,
    const float* __restrict__ meanp, const float* __restrict__ rstdp,
    const float* __restrict__ g1, const float* __restrict__ be1,
    const float* __restrict__ W2, const float* __restrict__ b2,
    const float* __restrict__ gnv, const float* __restrict__ bnv,
    const float* __restrict__ imgT, float* __restrict__ out) {
  __shared__ float smem[9344];
  float* w2s = smem;          // [8][800]
  float* us = smem + 6400;    // [8][32]
  float* ms = smem + 6656;    // [32]
  float* rs = smem + 6688;    // [32]

  const int bid = blockIdx.x;
  const int a = bid >> 4;
  const int o0 = (bid & 15) * 32;
  const int tid = threadIdx.x;
  const int tr = tid >> 5, tc = tid & 31;
  const int wv = tid >> 6, ln_ = tid & 63;

  if (tid < 32) {
    int o = o0 + tid;
    if (o < NOBJS) { int p = a * NOBJS + o; ms[tid] = meanp[p]; rs[tid] = rstdp[p]; }
    else { ms[tid] = 0.f; rs[tid] = 0.f; }
  }

  float acc[4][25];
  #pragma unroll
  for (int i = 0; i < 4; ++i)
    #pragma unroll
    for (int j = 0; j < 25; ++j) acc[i][j] = 0.f;

  const float* B1a = B1v + a * P_H1;
  const int o_l = tid >> 3, kk_u = tid & 7;
  const int ou = o0 + o_l;
  const bool ok_u = ou < NOBJS;
  const float* O1r = O1v + (ok_u ? ou : 0) * P_H1;

  for (int k0 = 0; k0 < P_H1; k0 += 8) {
    __syncthreads();
    {  // stage W2[k0:k0+8][0:800] (contiguous 6400 floats) via async copy
      const float* gsrc = W2 + k0 * 800;
      #pragma unroll
      for (int it = 0; it < 7; ++it) {
        int c0 = it * 256 + wv * 64;
        if (c0 < 1600) async_copy16(w2s + c0 * 4, gsrc + (c0 + ln_) * 4);
      }
    }
    {  // generate u chunk [8][32]
      int k = k0 + kk_u;
      float x = B1a[k] + (ok_u ? O1r[k] : 0.f);
      float un = (x - ms[o_l]) * rs[o_l] * g1[k] + be1[k];
      us[kk_u * 32 + o_l] = ok_u ? fmaxf(un, 0.f) : 0.f;
    }
    __syncthreads();
    for (int kk = 0; kk < 8; ++kk) {
      const float4 uv = *(const float4*)&us[kk * 32 + 4 * tr];
      const float* wrow = w2s + kk * 800 + tc;
      #pragma unroll
      for (int j = 0; j < 25; ++j) {
        float w = wrow[32 * j];
        acc[0][j] += uv.x * w;
        acc[1][j] += uv.y * w;
        acc[2][j] += uv.z * w;
        acc[3][j] += uv.w * w;
      }
    }
  }

  // LN2: bias, stats over 800 (row = 32 lanes x 25 cols), normalize
  float s1[4] = {0.f, 0.f, 0.f, 0.f}, s2[4] = {0.f, 0.f, 0.f, 0.f};
  #pragma unroll
  for (int j = 0; j < 25; ++j) {
    float bb = b2[tc + 32 * j];
    #pragma unroll
    for (int i = 0; i < 4; ++i) {
      float v = acc[i][j] + bb;
      acc[i][j] = v;
      s1[i] += v; s2[i] += v * v;
    }
  }
  #pragma unroll
  for (int m = 1; m < 32; m <<= 1) {
    #pragma unroll
    for (int i = 0; i < 4; ++i) { s1[i] += __shfl_xor(s1[i], m); s2[i] += __shfl_xor(s2[i], m); }
  }
  float mu[4], rsd[4];
  #pragma unroll
  for (int i = 0; i < 4; ++i) {
    float m_ = s1[i] * (1.f / EMB);
    mu[i] = m_;
    rsd[i] = rsqrtf(s2[i] * (1.f / EMB) - m_ * m_ + 1e-5f);
  }
  #pragma unroll
  for (int j = 0; j < 25; ++j) {
    int n = tc + 32 * j;
    float gg = gnv[n], bbn = bnv[n];
    #pragma unroll
    for (int i = 0; i < 4; ++i) acc[i][j] = (acc[i][j] - mu[i]) * rsd[i] * gg + bbn;
  }

  // GEMM3: out[b, p] = sum_n img_feats[b][n] * v[p][n], chunked over n
  float* vns = smem;          // [32][36]
  float* imgs = smem + 1152;  // [32][256]
  float acc3[4][8];
  #pragma unroll
  for (int i = 0; i < 4; ++i)
    #pragma unroll
    for (int jb = 0; jb < 8; ++jb) acc3[i][jb] = 0.f;

  for (int j = 0; j < 25; ++j) {
    __syncthreads();
    #pragma unroll
    for (int i = 0; i < 4; ++i) vns[tc * 36 + 4 * tr + i] = acc[i][j];
    {
      const float* gsrc = imgT + (32 * j) * BB;
      #pragma unroll
      for (int it = 0; it < 8; ++it) {
        int c0 = it * 256 + wv * 64;
        async_copy16(imgs + c0 * 4, gsrc + (c0 + ln_) * 4);
      }
    }
    __syncthreads();
    for (int nn = 0; nn < 32; ++nn) {
      const float4 v4 = *(const float4*)&vns[nn * 36 + 4 * tr];
      const float* irow = imgs + nn * 256 + tc;
      #pragma unroll
      for (int jb = 0; jb < 8; ++jb) {
        float ib = irow[32 * jb];
        acc3[0][jb] += v4.x * ib;
        acc3[1][jb] += v4.y * ib;
        acc3[2][jb] += v4.z * ib;
        acc3[3][jb] += v4.w * ib;
      }
    }
  }

  // store via LDS transpose for coalesced writes
  float* outs = smem;  // [256][33]
  __syncthreads();
  #pragma unroll
  for (int jb = 0; jb < 8; ++jb)
    #pragma unroll
    for (int i = 0; i < 4; ++i)
      outs[(tc + 32 * jb) * 33 + 4 * tr + i] = acc3[i][jb];
  __syncthreads();
  const int pbase = a * NOBJS + o0;
  for (int ii = 0; ii < 32; ++ii) {
    int idx = tid + 256 * ii;
    int p_l = idx & 31, b = idx >> 5;
    if (o0 + p_l < NOBJS) out[b * NPAIR + pbase + p_l] = outs[b * 33 + p_l];
  }
}

// ---------------- launch ----------------
extern "C" void kernel_launch(void* const* d_in, const int* in_sizes, int n_in,
                              void* d_out, int out_size, void* d_ws, size_t ws_size,
                              hipStream_t stream) {
  const float* img = (const float*)d_in[0];
  const float* node_feats = (const float*)d_in[1];
  const int* ei = (const int*)d_in[2];
  const float* s1_Wl = (const float*)d_in[3];
  const float* s1_bl = (const float*)d_in[4];
  const float* s1_Wr = (const float*)d_in[5];
  const float* s2_Wl = (const float*)d_in[6];
  const float* s2_bl = (const float*)d_in[7];
  const float* s2_Wr = (const float*)d_in[8];
  const float* i_W1 = (const float*)d_in[9];
  const float* i_b1 = (const float*)d_in[10];
  const float* i_g1 = (const float*)d_in[11];
  const float* i_be1 = (const float*)d_in[12];
  const float* i_W2 = (const float*)d_in[13];
  const float* i_b2 = (const float*)d_in[14];
  const float* i_g2 = (const float*)d_in[15];
  const float* i_be2 = (const float*)d_in[16];
  const float* i_W3 = (const float*)d_in[17];
  const float* i_b3 = (const float*)d_in[18];
  const float* i_gn = (const float*)d_in[19];
  const float* i_bn = (const float*)d_in[20];
  const float* p_W1 = (const float*)d_in[21];
  const float* p_b1 = (const float*)d_in[22];
  const float* p_g1 = (const float*)d_in[23];
  const float* p_be1 = (const float*)d_in[24];
  const float* p_W2 = (const float*)d_in[25];
  const float* p_b2 = (const float*)d_in[26];
  const float* p_gn = (const float*)d_in[27];
  const float* p_bn = (const float*)d_in[28];

  const int E = in_sizes[2] / 2;

  float* F = (float*)d_ws;
  float* mean1 = F;                 // 700*512
  float* h     = F + 358400;        // 700*2048
  float* mean2 = F + 1792000;       // 700*2048
  float* t1    = F + 3225600;       // 256*800
  float* t2    = F + 3430400;       // 256*1000
  float* t3    = F + 3686400;       // 256*800
  float* imgT  = F + 3891200;       // 800*256
  float* B1    = F + 4096000;       // 200*1000
  float* O1    = F + 4296000;       // 500*1000
  float* meanp = F + 4796000;       // 100000
  float* rstdp = F + 4896000;       // 100000
  int* cnt       = (int*)(F + 4996000);
  int* row_start = cnt + 704;
  int* pos       = row_start + 704;
  int* srcs      = pos + 704;

  float* pairp = (float*)d_out;
  float* nodes = (float*)d_out + (size_t)BB * NPAIR;

  // CSR build
  hipMemsetAsync(cnt, 0, NNODE * sizeof(int), stream);
  k_count<<<(E + 255) / 256, 256, 0, stream>>>(ei, cnt, E);
  k_scan<<<1, 1024, 0, stream>>>(cnt, row_start, pos);
  k_fill<<<(E + 255) / 256, 256, 0, stream>>>(ei, pos, srcs, E);

  // SAGE layer 1: h = relu(mean1@Wl + feats@Wr + bl)
  agg_mean<<<dim3(NNODE, IN_F / 256), 256, 0, stream>>>(node_feats, srcs, row_start, mean1, IN_F);
  gemm_f32<1, true, true><<<dim3(HID / 64, (NNODE + 63) / 64), 256, 0, stream>>>(
      mean1, s1_Wl, node_feats, s1_Wr, s1_bl, h, NNODE, HID, IN_F);
  // SAGE layer 2: nodes = mean2@Wl + h@Wr + bl
  agg_mean<<<dim3(NNODE, HID / 256), 256, 0, stream>>>(h, srcs, row_start, mean2, HID);
  gemm_f32<0, true, true><<<dim3(NODE_D / 64, (NNODE + 63) / 64), 256, 0, stream>>>(
      mean2, s2_Wl, h, s2_Wr, s2_bl, nodes, NNODE, NODE_D, HID);

  // image branch
  gemm_f32<0, false, true><<<dim3((800 + 63) / 64, BB / 64), 256, 0, stream>>>(
      img, i_W1, nullptr, nullptr, i_b1, t1, BB, 800, IMG_D);
  ln_rows<true><<<BB, 256, 0, stream>>>(t1, i_g1, i_be1, 800);
  gemm_f32<0, false, true><<<dim3((1000 + 63) / 64, BB / 64), 256, 0, stream>>>(
      t1, i_W2, nullptr, nullptr, i_b2, t2, BB, 1000, 800);
  ln_rows<true><<<BB, 256, 0, stream>>>(t2, i_g2, i_be2, 1000);
  gemm_f32<0, false, true><<<dim3((EMB + 63) / 64, BB / 64), 256, 0, stream>>>(
      t2, i_W3, nullptr, nullptr, i_b3, t3, BB, EMB, 1000);
  ln_rows<false><<<BB, 256, 0, stream>>>(t3, i_gn, i_bn, EMB);
  transpose_img<<<EMB, BB, 0, stream>>>(t3, imgT);

  // pair branch factored first GEMM
  gemm_f32<0, false, true><<<dim3((P_H1 + 63) / 64, (NATTRS + 63) / 64), 256, 0, stream>>>(
      nodes, p_W1, nullptr, nullptr, p_b1, B1, NATTRS, P_H1, NODE_D);
  gemm_f32<0, false, false><<<dim3((P_H1 + 63) / 64, (NOBJS + 63) / 64), 256, 0, stream>>>(
      nodes + NATTRS * NODE_D, p_W1 + NODE_D * P_H1, nullptr, nullptr, nullptr, O1, NOBJS, P_H1, NODE_D);

  pair_stats<<<NPAIR / 4, 256, 0, stream>>>(B1, O1, meanp, rstdp);
  pair_mega<<<NATTRS * 16, 256, 0, stream>>>(B1, O1, meanp, rstdp, p_g1, p_be1,
                                             p_W2, p_b2, p_gn, p_bn, imgT, pairp);
}

// Round 3
// 3064.162 us; speedup vs baseline: 3.7560x; 3.7560x over previous
//
#include <hip/hip_runtime.h>
#include <hip/hip_bf16.h>

#define NATTRS 200
#define NOBJS  500
#define NNODE  700
#define IN_F   512
#define HID    2048
#define NODE_D 512
#define IMG_D  512
#define EMB    800
#define BB     256
#define P_H1   1000
#define NPAIR  100000

typedef __attribute__((ext_vector_type(8))) short short8v;
typedef __attribute__((ext_vector_type(4))) float f32x4;

// ---------------- async global->LDS (16B) ----------------
typedef const __attribute__((address_space(1))) unsigned int* gas_ptr;
typedef __attribute__((address_space(3))) unsigned int* las_ptr;
__device__ __forceinline__ void async_copy16(void* lds, const void* g) {
  __builtin_amdgcn_global_load_lds((gas_ptr)g, (las_ptr)lds, 16, 0, 0);
}

__device__ __forceinline__ ushort f2bf(float x) {
  __hip_bfloat16 b = __float2bfloat16(x);
  return *reinterpret_cast<ushort*>(&b);
}
__device__ __forceinline__ float bf2f(ushort u) {
  __hip_bfloat16 b;
  *reinterpret_cast<ushort*>(&b) = u;
  return __bfloat162float(b);
}

// ---------------- CSR build ----------------
__global__ void k_count(const int* __restrict__ ei, int* __restrict__ cnt, int E) {
  int e = blockIdx.x * 256 + threadIdx.x;
  if (e < E) atomicAdd(&cnt[ei[E + e]], 1);
}

__global__ __launch_bounds__(1024) void k_scan(const int* __restrict__ cnt,
                                               int* __restrict__ row_start,
                                               int* __restrict__ pos) {
  __shared__ int s[1024];
  int t = threadIdx.x;
  int my = (t < NNODE) ? cnt[t] : 0;
  s[t] = my;
  __syncthreads();
  for (int off = 1; off < 1024; off <<= 1) {
    int add = (t >= off) ? s[t - off] : 0;
    __syncthreads();
    s[t] += add;
    __syncthreads();
  }
  int excl = s[t] - my;
  if (t < NNODE) { row_start[t] = excl; pos[t] = excl; }
  if (t == 0) row_start[NNODE] = s[1023];
}

__global__ void k_fill(const int* __restrict__ ei, int* __restrict__ pos,
                       int* __restrict__ srcs, int E) {
  int e = blockIdx.x * 256 + threadIdx.x;
  if (e < E) {
    int d = ei[E + e];
    int idx = atomicAdd(&pos[d], 1);
    srcs[idx] = ei[e];
  }
}

__global__ __launch_bounds__(256) void agg_mean(const float* __restrict__ X,
                                                const int* __restrict__ srcs,
                                                const int* __restrict__ row_start,
                                                float* __restrict__ outp, int D) {
  int node = blockIdx.x;
  int d = blockIdx.y * 256 + threadIdx.x;
  int e0 = row_start[node], e1 = row_start[node + 1];
  float s = 0.f;
  for (int e = e0; e < e1; ++e) s += X[srcs[e] * D + d];
  float c = (float)(e1 - e0);
  outp[node * D + d] = s / fmaxf(c, 1.f);
}

// ---------------- generic small GEMM: C = act(A@B (+A2@B2) + bias) ----------------
template <int ACT, bool HAS2, bool HASB>
__global__ __launch_bounds__(256) void gemm_f32(const float* __restrict__ A,
                                                const float* __restrict__ B,
                                                const float* __restrict__ A2,
                                                const float* __restrict__ B2,
                                                const float* __restrict__ bias,
                                                float* __restrict__ C,
                                                int M, int N, int K) {
  __shared__ float As[16][68];
  __shared__ float Bs[16][64];
  const int n0 = blockIdx.x * 64, m0 = blockIdx.y * 64;
  const int tid = threadIdx.x;
  const int ty = tid >> 4, tx = tid & 15;
  float acc[4][4] = {};
  const int npass = HAS2 ? 2 : 1;
  for (int pass = 0; pass < npass; ++pass) {
    const float* Ap = (HAS2 && pass) ? A2 : A;
    const float* Bp = (HAS2 && pass) ? B2 : B;
    for (int k0 = 0; k0 < K; k0 += 16) {
      __syncthreads();
      #pragma unroll
      for (int ii = 0; ii < 4; ++ii) {
        int idx = tid + 256 * ii;
        int m = idx >> 4, k = idx & 15;
        float v = 0.f;
        if (m0 + m < M && k0 + k < K) v = Ap[(m0 + m) * K + k0 + k];
        As[k][m] = v;
      }
      #pragma unroll
      for (int ii = 0; ii < 4; ++ii) {
        int idx = tid + 256 * ii;
        int k = idx >> 6, n = idx & 63;
        float v = 0.f;
        if (k0 + k < K && n0 + n < N) v = Bp[(k0 + k) * N + n0 + n];
        Bs[k][n] = v;
      }
      __syncthreads();
      #pragma unroll
      for (int kk = 0; kk < 16; ++kk) {
        const float4 a4 = *(const float4*)&As[kk][4 * ty];
        const float4 b4 = *(const float4*)&Bs[kk][4 * tx];
        acc[0][0] += a4.x * b4.x; acc[0][1] += a4.x * b4.y; acc[0][2] += a4.x * b4.z; acc[0][3] += a4.x * b4.w;
        acc[1][0] += a4.y * b4.x; acc[1][1] += a4.y * b4.y; acc[1][2] += a4.y * b4.z; acc[1][3] += a4.y * b4.w;
        acc[2][0] += a4.z * b4.x; acc[2][1] += a4.z * b4.y; acc[2][2] += a4.z * b4.z; acc[2][3] += a4.z * b4.w;
        acc[3][0] += a4.w * b4.x; acc[3][1] += a4.w * b4.y; acc[3][2] += a4.w * b4.z; acc[3][3] += a4.w * b4.w;
      }
    }
  }
  #pragma unroll
  for (int i = 0; i < 4; ++i) {
    int m = m0 + 4 * ty + i;
    if (m >= M) continue;
    #pragma unroll
    for (int j = 0; j < 4; ++j) {
      int n = n0 + 4 * tx + j;
      if (n >= N) continue;
      float v = acc[i][j];
      if (HASB) v += bias[n];
      if (ACT == 1) v = fmaxf(v, 0.f);
      C[m * N + n] = v;
    }
  }
}

// ---------------- row LayerNorm (in-place), optional relu ----------------
template <bool RELU>
__global__ __launch_bounds__(256) void ln_rows(float* __restrict__ X,
                                               const float* __restrict__ g,
                                               const float* __restrict__ b, int N) {
  int row = blockIdx.x, tid = threadIdx.x;
  float* x = X + row * N;
  float s1 = 0.f, s2 = 0.f;
  for (int i = tid; i < N; i += 256) { float v = x[i]; s1 += v; s2 += v * v; }
  #pragma unroll
  for (int m = 1; m < 64; m <<= 1) { s1 += __shfl_xor(s1, m); s2 += __shfl_xor(s2, m); }
  __shared__ float r1[4], r2[4];
  int wv = tid >> 6;
  if ((tid & 63) == 0) { r1[wv] = s1; r2[wv] = s2; }
  __syncthreads();
  s1 = r1[0] + r1[1] + r1[2] + r1[3];
  s2 = r2[0] + r2[1] + r2[2] + r2[3];
  float inv = 1.f / (float)N;
  float mu = s1 * inv;
  float rstd = rsqrtf(s2 * inv - mu * mu + 1e-5f);
  for (int i = tid; i < N; i += 256) {
    float v = (x[i] - mu) * rstd * g[i] + b[i];
    if (RELU) v = fmaxf(v, 0.f);
    x[i] = v;
  }
}

// ---------------- prep: W2 [1000][800] f32 -> W2T hi/lo [896][1024] bf16 ----------------
__global__ __launch_bounds__(256) void prep_w2(const float* __restrict__ W2,
                                               ushort* __restrict__ Wh,
                                               ushort* __restrict__ Wl) {
  int n = blockIdx.x;  // 0..895
  for (int k = threadIdx.x; k < 1024; k += 256) {
    float w = (n < EMB && k < P_H1) ? W2[k * EMB + n] : 0.f;
    ushort h = f2bf(w);
    Wh[n * 1024 + k] = h;
    Wl[n * 1024 + k] = f2bf(w - bf2f(h));
  }
}

// ---------------- prep: img_feats f32 -> hi/lo bf16 [256][800] ----------------
__global__ __launch_bounds__(256) void prep_img(const float* __restrict__ t3,
                                                ushort* __restrict__ ih,
                                                ushort* __restrict__ il) {
  int r = blockIdx.x;  // 0..255
  for (int n = threadIdx.x; n < EMB; n += 256) {
    float v = t3[r * EMB + n];
    ushort h = f2bf(v);
    ih[r * EMB + n] = h;
    il[r * EMB + n] = f2bf(v - bf2f(h));
  }
}

// ---------------- ugen: U[p][k]=relu(LN1(B1[a]+O1[o])) -> bf16 hi/lo [rowsPad][1024] ----------------
__global__ __launch_bounds__(256) void ugen(const float* __restrict__ B1v,
                                            const float* __restrict__ O1v,
                                            const float* __restrict__ g1,
                                            const float* __restrict__ be1,
                                            ushort* __restrict__ Uh,
                                            ushort* __restrict__ Ul, int p0) {
  int r = blockIdx.x * 4 + (threadIdx.x >> 6);
  int lane = threadIdx.x & 63;
  int p = p0 + r;
  if (p > NPAIR - 1) p = NPAIR - 1;  // clamp pad rows to a valid pair
  int a = p / NOBJS, o = p - a * NOBJS;
  const float* br = B1v + a * P_H1;
  const float* ow = O1v + o * P_H1;
  float x[16];
  float s1 = 0.f, s2 = 0.f;
  #pragma unroll
  for (int i = 0; i < 16; ++i) {
    int k = lane + 64 * i;
    float v = 0.f;
    if (k < P_H1) v = br[k] + ow[k];
    x[i] = v; s1 += v; s2 += v * v;
  }
  #pragma unroll
  for (int m = 1; m < 64; m <<= 1) { s1 += __shfl_xor(s1, m); s2 += __shfl_xor(s2, m); }
  float mu = s1 * (1.f / P_H1);
  float rstd = rsqrtf(s2 * (1.f / P_H1) - mu * mu + 1e-5f);
  size_t rb = (size_t)r * 1024;
  #pragma unroll
  for (int i = 0; i < 16; ++i) {
    int k = lane + 64 * i;
    float un = 0.f;
    if (k < P_H1) un = fmaxf((x[i] - mu) * rstd * g1[k] + be1[k], 0.f);
    ushort h = f2bf(un);
    Uh[rb + k] = h;
    Ul[rb + k] = f2bf(un - bf2f(h));
  }
}

// ---------------- ln2k: Vn = LN2(V_raw) -> bf16 hi/lo [rowsPad][800] ----------------
__global__ __launch_bounds__(256) void ln2k(const float* __restrict__ Vr,
                                            const float* __restrict__ gn,
                                            const float* __restrict__ bn,
                                            ushort* __restrict__ Vh,
                                            ushort* __restrict__ Vl) {
  int r = blockIdx.x * 4 + (threadIdx.x >> 6);
  int lane = threadIdx.x & 63;
  const float* row = Vr + (size_t)r * EMB;
  float x[13];
  float s1 = 0.f, s2 = 0.f;
  #pragma unroll
  for (int i = 0; i < 13; ++i) {
    int k = lane + 64 * i;
    float v = (k < EMB) ? row[k] : 0.f;
    x[i] = v; s1 += v; s2 += v * v;
  }
  #pragma unroll
  for (int m = 1; m < 64; m <<= 1) { s1 += __shfl_xor(s1, m); s2 += __shfl_xor(s2, m); }
  float mu = s1 * (1.f / EMB);
  float rstd = rsqrtf(s2 * (1.f / EMB) - mu * mu + 1e-5f);
  size_t rb = (size_t)r * EMB;
  #pragma unroll
  for (int i = 0; i < 13; ++i) {
    int k = lane + 64 * i;
    if (k < EMB) {
      float v = (x[i] - mu) * rstd * gn[k] + bn[k];
      ushort h = f2bf(v);
      Vh[rb + k] = h;
      Vl[rb + k] = f2bf(v - bf2f(h));
    }
  }
}

// ---------------- bf16 hi/lo split MFMA GEMM (both operands K-contiguous row-major) ----
// C[m][n] = sum_k (Ah+Al)[m][k]*(Bh+Bl)[n][k]   (3-product: hh + lh + hl)
// 128x128 tile, BK=32, 4 waves (2x2), m97-style 2-barrier global_load_lds staging.
template <bool HASBIAS>
__global__ __launch_bounds__(256, 3) void gemm_bt3(
    const ushort* __restrict__ Ah, const ushort* __restrict__ Al, int lda,
    const ushort* __restrict__ Bh, const ushort* __restrict__ Bl, int ldb,
    const float* __restrict__ bias, float* __restrict__ C, size_t ldc,
    int K, int nvalid, int ncol0) {
  __shared__ ushort smem[16384];  // 4 x [128][32] bf16 tiles (Ah,Al,Bh,Bl), 32 KB
  const int tid = threadIdx.x, lane = tid & 63, wid = tid >> 6;
  const int wm = wid >> 1, wn = wid & 1;  // 2x2 wave grid, 64x64 per wave
  const int n0b = blockIdx.x * 128, m0 = blockIdx.y * 128;
  const int lr = lane & 15, lk = lane >> 4;

  f32x4 acc[4][4];
  #pragma unroll
  for (int i = 0; i < 4; ++i)
    #pragma unroll
    for (int j = 0; j < 4; ++j) acc[i][j] = (f32x4){0.f, 0.f, 0.f, 0.f};

  const int srow = lane >> 2;          // staging row within 16-row group
  const int scol = (lane & 3) * 8;     // staging col (bf16 elems)

  for (int k0 = 0; k0 < K; k0 += 32) {
    __syncthreads();
    #pragma unroll
    for (int j = 0; j < 8; ++j) {
      int t = wid + 4 * j;  // wave-uniform issue id 0..31
      int buf = t >> 3, i = t & 7;
      const ushort* g;
      int ld_, r0;
      if (buf == 0)      { g = Ah; ld_ = lda; r0 = m0; }
      else if (buf == 1) { g = Al; ld_ = lda; r0 = m0; }
      else if (buf == 2) { g = Bh; ld_ = ldb; r0 = n0b; }
      else               { g = Bl; ld_ = ldb; r0 = n0b; }
      const ushort* src = g + (size_t)(r0 + i * 16 + srow) * ld_ + k0 + scol;
      async_copy16(smem + buf * 4096 + i * 512, src);
    }
    __syncthreads();

    short8v ah[4], al[4], bh[4], bl[4];
    #pragma unroll
    for (int f = 0; f < 4; ++f) {
      ah[f] = *(const short8v*)&smem[0     + (wm * 64 + f * 16 + lr) * 32 + lk * 8];
      al[f] = *(const short8v*)&smem[4096  + (wm * 64 + f * 16 + lr) * 32 + lk * 8];
      bh[f] = *(const short8v*)&smem[8192  + (wn * 64 + f * 16 + lr) * 32 + lk * 8];
      bl[f] = *(const short8v*)&smem[12288 + (wn * 64 + f * 16 + lr) * 32 + lk * 8];
    }
    #pragma unroll
    for (int mi = 0; mi < 4; ++mi)
      #pragma unroll
      for (int ni = 0; ni < 4; ++ni) {
        acc[mi][ni] = __builtin_amdgcn_mfma_f32_16x16x32_bf16(ah[mi], bh[ni], acc[mi][ni], 0, 0, 0);
        acc[mi][ni] = __builtin_amdgcn_mfma_f32_16x16x32_bf16(al[mi], bh[ni], acc[mi][ni], 0, 0, 0);
        acc[mi][ni] = __builtin_amdgcn_mfma_f32_16x16x32_bf16(ah[mi], bl[ni], acc[mi][ni], 0, 0, 0);
      }
  }

  // epilogue: C/D layout col=lane&15, row=(lane>>4)*4+reg  [m89-verified]
  #pragma unroll
  for (int mi = 0; mi < 4; ++mi)
    #pragma unroll
    for (int ni = 0; ni < 4; ++ni) {
      #pragma unroll
      for (int r = 0; r < 4; ++r) {
        int m = m0 + wm * 64 + mi * 16 + lk * 4 + r;
        int n = blockIdx.x * 128 + wn * 64 + ni * 16 + lr;
        if (n < nvalid) {
          float v = acc[mi][ni][r];
          if (HASBIAS) v += bias[n];
          C[(size_t)m * ldc + ncol0 + n] = v;
        }
      }
    }
}

// ---------------- launch ----------------
extern "C" void kernel_launch(void* const* d_in, const int* in_sizes, int n_in,
                              void* d_out, int out_size, void* d_ws, size_t ws_size,
                              hipStream_t stream) {
  const float* img = (const float*)d_in[0];
  const float* node_feats = (const float*)d_in[1];
  const int* ei = (const int*)d_in[2];
  const float* s1_Wl = (const float*)d_in[3];
  const float* s1_bl = (const float*)d_in[4];
  const float* s1_Wr = (const float*)d_in[5];
  const float* s2_Wl = (const float*)d_in[6];
  const float* s2_bl = (const float*)d_in[7];
  const float* s2_Wr = (const float*)d_in[8];
  const float* i_W1 = (const float*)d_in[9];
  const float* i_b1 = (const float*)d_in[10];
  const float* i_g1 = (const float*)d_in[11];
  const float* i_be1 = (const float*)d_in[12];
  const float* i_W2 = (const float*)d_in[13];
  const float* i_b2 = (const float*)d_in[14];
  const float* i_g2 = (const float*)d_in[15];
  const float* i_be2 = (const float*)d_in[16];
  const float* i_W3 = (const float*)d_in[17];
  const float* i_b3 = (const float*)d_in[18];
  const float* i_gn = (const float*)d_in[19];
  const float* i_bn = (const float*)d_in[20];
  const float* p_W1 = (const float*)d_in[21];
  const float* p_b1 = (const float*)d_in[22];
  const float* p_g1 = (const float*)d_in[23];
  const float* p_be1 = (const float*)d_in[24];
  const float* p_W2 = (const float*)d_in[25];
  const float* p_b2 = (const float*)d_in[26];
  const float* p_gn = (const float*)d_in[27];
  const float* p_bn = (const float*)d_in[28];

  const int E = in_sizes[2] / 2;

  // -------- workspace layout --------
  char* base = (char*)d_ws;
  size_t off = 0;
  auto alloc = [&](size_t bytes) -> void* {
    void* p = base + off;
    off = (off + bytes + 255) & ~(size_t)255;
    return p;
  };
  float* mean1 = (float*)alloc(700 * 512 * 4);
  float* h     = (float*)alloc(700 * 2048 * 4);
  float* mean2 = (float*)alloc(700 * 2048 * 4);
  float* t1    = (float*)alloc(256 * 800 * 4);
  float* t2    = (float*)alloc(256 * 1000 * 4);
  float* t3    = (float*)alloc(256 * 800 * 4);
  float* B1    = (float*)alloc(200 * 1000 * 4);
  float* O1    = (float*)alloc(500 * 1000 * 4);
  ushort* imgh = (ushort*)alloc(256 * 800 * 2);
  ushort* imgl = (ushort*)alloc(256 * 800 * 2);
  ushort* W2Th = (ushort*)alloc(896 * 1024 * 2);
  ushort* W2Tl = (ushort*)alloc(896 * 1024 * 2);
  int* cnt       = (int*)alloc(704 * 4);
  int* row_start = (int*)alloc(704 * 4);
  int* pos       = (int*)alloc(704 * 4);
  int* srcs      = (int*)alloc(50176 * 4);

  // chunked pair-branch buffers: per row 1024*2*2 (U) + 800*4 (Vraw) + 800*2*2 (Vn) = 10496 B
  size_t avail = (ws_size > off + (4u << 20)) ? ws_size - off - (4u << 20) : 0;
  long maxRows = (long)(avail / 10496) - 128;
  int CA = (int)(maxRows / 500);
  if (CA < 1) CA = 1;
  if (CA > 50) CA = 50;
  int nch = (NATTRS + CA - 1) / CA;
  int rowsPadAlloc = ((CA * 500 + 127) / 128) * 128;
  ushort* Uh   = (ushort*)alloc((size_t)rowsPadAlloc * 1024 * 2);
  ushort* Ul   = (ushort*)alloc((size_t)rowsPadAlloc * 1024 * 2);
  float*  Vraw = (float*) alloc((size_t)rowsPadAlloc * 800 * 4);
  ushort* Vh   = (ushort*)alloc((size_t)rowsPadAlloc * 800 * 2);
  ushort* Vl   = (ushort*)alloc((size_t)rowsPadAlloc * 800 * 2);

  float* pairp = (float*)d_out;
  float* nodes = (float*)d_out + (size_t)BB * NPAIR;

  // -------- CSR build --------
  hipMemsetAsync(cnt, 0, NNODE * sizeof(int), stream);
  k_count<<<(E + 255) / 256, 256, 0, stream>>>(ei, cnt, E);
  k_scan<<<1, 1024, 0, stream>>>(cnt, row_start, pos);
  k_fill<<<(E + 255) / 256, 256, 0, stream>>>(ei, pos, srcs, E);

  // -------- SAGE --------
  agg_mean<<<dim3(NNODE, IN_F / 256), 256, 0, stream>>>(node_feats, srcs, row_start, mean1, IN_F);
  gemm_f32<1, true, true><<<dim3(HID / 64, (NNODE + 63) / 64), 256, 0, stream>>>(
      mean1, s1_Wl, node_feats, s1_Wr, s1_bl, h, NNODE, HID, IN_F);
  agg_mean<<<dim3(NNODE, HID / 256), 256, 0, stream>>>(h, srcs, row_start, mean2, HID);
  gemm_f32<0, true, true><<<dim3(NODE_D / 64, (NNODE + 63) / 64), 256, 0, stream>>>(
      mean2, s2_Wl, h, s2_Wr, s2_bl, nodes, NNODE, NODE_D, HID);

  // -------- image branch --------
  gemm_f32<0, false, true><<<dim3((800 + 63) / 64, BB / 64), 256, 0, stream>>>(
      img, i_W1, nullptr, nullptr, i_b1, t1, BB, 800, IMG_D);
  ln_rows<true><<<BB, 256, 0, stream>>>(t1, i_g1, i_be1, 800);
  gemm_f32<0, false, true><<<dim3((1000 + 63) / 64, BB / 64), 256, 0, stream>>>(
      t1, i_W2, nullptr, nullptr, i_b2, t2, BB, 1000, 800);
  ln_rows<true><<<BB, 256, 0, stream>>>(t2, i_g2, i_be2, 1000);
  gemm_f32<0, false, true><<<dim3((EMB + 63) / 64, BB / 64), 256, 0, stream>>>(
      t2, i_W3, nullptr, nullptr, i_b3, t3, BB, EMB, 1000);
  ln_rows<false><<<BB, 256, 0, stream>>>(t3, i_gn, i_bn, EMB);
  prep_img<<<BB, 256, 0, stream>>>(t3, imgh, imgl);

  // -------- pair-branch prep --------
  prep_w2<<<896, 256, 0, stream>>>(p_W2, W2Th, W2Tl);
  gemm_f32<0, false, true><<<dim3((P_H1 + 63) / 64, (NATTRS + 63) / 64), 256, 0, stream>>>(
      nodes, p_W1, nullptr, nullptr, p_b1, B1, NATTRS, P_H1, NODE_D);
  gemm_f32<0, false, false><<<dim3((P_H1 + 63) / 64, (NOBJS + 63) / 64), 256, 0, stream>>>(
      nodes + NATTRS * NODE_D, p_W1 + NODE_D * P_H1, nullptr, nullptr, nullptr, O1, NOBJS, P_H1, NODE_D);

  // -------- chunked pair branch: ugen -> GEMM2 (MFMA) -> LN2 -> GEMM3 (MFMA) --------
  for (int c = 0; c < nch; ++c) {
    int a0 = c * CA;
    int ca = (NATTRS - a0 < CA) ? (NATTRS - a0) : CA;
    int rows = ca * 500;
    int rowsPad = ((rows + 127) / 128) * 128;
    int p0 = a0 * 500;

    ugen<<<rowsPad / 4, 256, 0, stream>>>(B1, O1, p_g1, p_be1, Uh, Ul, p0);
    // V_raw[rows][800] = U @ W2 + b2  (M=rowsPad, N=896 padded, K=1024 padded)
    gemm_bt3<true><<<dim3(7, rowsPad / 128), 256, 0, stream>>>(
        Uh, Ul, 1024, W2Th, W2Tl, 1024, p_b2, Vraw, 800, 1024, 800, 0);
    ln2k<<<rowsPad / 4, 256, 0, stream>>>(Vraw, p_gn, p_bn, Vh, Vl);
    // out[b][p0+p] = img_feats @ Vn^T  (M=256, N=rowsPad pairs, K=800)
    gemm_bt3<false><<<dim3(rowsPad / 128, 2), 256, 0, stream>>>(
        imgh, imgl, 800, Vh, Vl, 800, nullptr, pairp, NPAIR, 800, rows, p0);
  }
}

// Round 4
// 1892.480 us; speedup vs baseline: 6.0815x; 1.6191x over previous
//
#include <hip/hip_runtime.h>
#include <hip/hip_bf16.h>

#define NATTRS 200
#define NOBJS  500
#define NNODE  700
#define IN_F   512
#define HID    2048
#define NODE_D 512
#define IMG_D  512
#define EMB    800
#define BB     256
#define P_H1   1000
#define NPAIR  100000

typedef __attribute__((ext_vector_type(8))) short short8v;
typedef __attribute__((ext_vector_type(4))) float f32x4;

// ---------------- async global->LDS (16B) ----------------
typedef const __attribute__((address_space(1))) unsigned int* gas_ptr;
typedef __attribute__((address_space(3))) unsigned int* las_ptr;
__device__ __forceinline__ void async_copy16(void* lds, const void* g) {
  __builtin_amdgcn_global_load_lds((gas_ptr)g, (las_ptr)lds, 16, 0, 0);
}

__device__ __forceinline__ ushort f2bf(float x) {
  __hip_bfloat16 b = __float2bfloat16(x);
  return *reinterpret_cast<ushort*>(&b);
}
__device__ __forceinline__ float bf2f(ushort u) {
  __hip_bfloat16 b;
  *reinterpret_cast<ushort*>(&b) = u;
  return __bfloat162float(b);
}

// ---------------- CSR build ----------------
__global__ void k_count(const int* __restrict__ ei, int* __restrict__ cnt, int E) {
  int e = blockIdx.x * 256 + threadIdx.x;
  if (e < E) atomicAdd(&cnt[ei[E + e]], 1);
}

__global__ __launch_bounds__(1024) void k_scan(const int* __restrict__ cnt,
                                               int* __restrict__ row_start,
                                               int* __restrict__ pos) {
  __shared__ int s[1024];
  int t = threadIdx.x;
  int my = (t < NNODE) ? cnt[t] : 0;
  s[t] = my;
  __syncthreads();
  for (int off = 1; off < 1024; off <<= 1) {
    int add = (t >= off) ? s[t - off] : 0;
    __syncthreads();
    s[t] += add;
    __syncthreads();
  }
  int excl = s[t] - my;
  if (t < NNODE) { row_start[t] = excl; pos[t] = excl; }
  if (t == 0) row_start[NNODE] = s[1023];
}

__global__ void k_fill(const int* __restrict__ ei, int* __restrict__ pos,
                       int* __restrict__ srcs, int E) {
  int e = blockIdx.x * 256 + threadIdx.x;
  if (e < E) {
    int d = ei[E + e];
    int idx = atomicAdd(&pos[d], 1);
    srcs[idx] = ei[e];
  }
}

__global__ __launch_bounds__(256) void agg_mean(const float* __restrict__ X,
                                                const int* __restrict__ srcs,
                                                const int* __restrict__ row_start,
                                                float* __restrict__ outp, int D) {
  int node = blockIdx.x;
  int d = blockIdx.y * 256 + threadIdx.x;
  int e0 = row_start[node], e1 = row_start[node + 1];
  float s = 0.f;
  for (int e = e0; e < e1; ++e) s += X[srcs[e] * D + d];
  float c = (float)(e1 - e0);
  outp[node * D + d] = s / fmaxf(c, 1.f);
}

// ---------------- split: X f32 [Mvalid][K] -> hi/lo bf16 [Mpad][Kpad], zero pad ----------------
__global__ __launch_bounds__(256) void split_f32(const float* __restrict__ X,
                                                 ushort* __restrict__ Xh,
                                                 ushort* __restrict__ Xl,
                                                 int Mvalid, int K, int Kpad, long total) {
  for (long idx = blockIdx.x * 256L + threadIdx.x; idx < total; idx += gridDim.x * 256L) {
    int m = (int)(idx / Kpad);
    int k = (int)(idx - (long)m * Kpad);
    float v = (m < Mvalid && k < K) ? X[(size_t)m * K + k] : 0.f;
    ushort h = f2bf(v);
    Xh[idx] = h;
    Xl[idx] = f2bf(v - bf2f(h));
  }
}

// ---------------- prep_wT: W f32 [K][N] -> Wh/Wl bf16 [Npad][Kpad] (transposed), zero pad ----
__global__ __launch_bounds__(256) void prep_wT(const float* __restrict__ W,
                                               ushort* __restrict__ Wh,
                                               ushort* __restrict__ Wl,
                                               int K, int N, int Kpad) {
  __shared__ float tile[32][33];
  const int n0 = blockIdx.x * 32, k0 = blockIdx.y * 32;
  const int tx = threadIdx.x & 31, ty = threadIdx.x >> 5;  // 32 x 8
  #pragma unroll
  for (int r0 = 0; r0 < 32; r0 += 8) {
    int k = k0 + r0 + ty, n = n0 + tx;
    tile[r0 + ty][tx] = (k < K && n < N) ? W[(size_t)k * N + n] : 0.f;
  }
  __syncthreads();
  #pragma unroll
  for (int r0 = 0; r0 < 32; r0 += 8) {
    int n = n0 + r0 + ty, kk = k0 + tx;
    float v = tile[tx][r0 + ty];
    ushort h = f2bf(v);
    Wh[(size_t)n * Kpad + kk] = h;
    Wl[(size_t)n * Kpad + kk] = f2bf(v - bf2f(h));
  }
}

// ---------------- row LayerNorm (in-place), optional relu ----------------
template <bool RELU>
__global__ __launch_bounds__(256) void ln_rows(float* __restrict__ X,
                                               const float* __restrict__ g,
                                               const float* __restrict__ b, int N) {
  int row = blockIdx.x, tid = threadIdx.x;
  float* x = X + row * N;
  float s1 = 0.f, s2 = 0.f;
  for (int i = tid; i < N; i += 256) { float v = x[i]; s1 += v; s2 += v * v; }
  #pragma unroll
  for (int m = 1; m < 64; m <<= 1) { s1 += __shfl_xor(s1, m); s2 += __shfl_xor(s2, m); }
  __shared__ float r1[4], r2[4];
  int wv = tid >> 6;
  if ((tid & 63) == 0) { r1[wv] = s1; r2[wv] = s2; }
  __syncthreads();
  s1 = r1[0] + r1[1] + r1[2] + r1[3];
  s2 = r2[0] + r2[1] + r2[2] + r2[3];
  float inv = 1.f / (float)N;
  float mu = s1 * inv;
  float rstd = rsqrtf(s2 * inv - mu * mu + 1e-5f);
  for (int i = tid; i < N; i += 256) {
    float v = (x[i] - mu) * rstd * g[i] + b[i];
    if (RELU) v = fmaxf(v, 0.f);
    x[i] = v;
  }
}

// ---------------- prep: img_feats f32 -> hi/lo bf16 [256][800] ----------------
__global__ __launch_bounds__(256) void prep_img(const float* __restrict__ t3,
                                                ushort* __restrict__ ih,
                                                ushort* __restrict__ il) {
  int r = blockIdx.x;
  for (int n = threadIdx.x; n < EMB; n += 256) {
    float v = t3[r * EMB + n];
    ushort h = f2bf(v);
    ih[r * EMB + n] = h;
    il[r * EMB + n] = f2bf(v - bf2f(h));
  }
}

// ---------------- ugen: U[p][k]=relu(LN1(B1[a]+O1[o])) -> bf16 hi/lo [rowsPad][1024] -------
__global__ __launch_bounds__(256) void ugen(const float* __restrict__ B1v,
                                            const float* __restrict__ O1v,
                                            const float* __restrict__ g1,
                                            const float* __restrict__ be1,
                                            ushort* __restrict__ Uh,
                                            ushort* __restrict__ Ul, int p0) {
  int r = blockIdx.x * 4 + (threadIdx.x >> 6);
  int lane = threadIdx.x & 63;
  int p = p0 + r;
  if (p > NPAIR - 1) p = NPAIR - 1;
  int a = p / NOBJS, o = p - a * NOBJS;
  const float* br = B1v + a * P_H1;
  const float* ow = O1v + o * P_H1;
  float x[16];
  float s1 = 0.f, s2 = 0.f;
  #pragma unroll
  for (int i = 0; i < 16; ++i) {
    int k = lane + 64 * i;
    float v = 0.f;
    if (k < P_H1) v = br[k] + ow[k];
    x[i] = v; s1 += v; s2 += v * v;
  }
  #pragma unroll
  for (int m = 1; m < 64; m <<= 1) { s1 += __shfl_xor(s1, m); s2 += __shfl_xor(s2, m); }
  float mu = s1 * (1.f / P_H1);
  float rstd = rsqrtf(s2 * (1.f / P_H1) - mu * mu + 1e-5f);
  size_t rb = (size_t)r * 1024;
  #pragma unroll
  for (int i = 0; i < 16; ++i) {
    int k = lane + 64 * i;
    float un = 0.f;
    if (k < P_H1) un = fmaxf((x[i] - mu) * rstd * g1[k] + be1[k], 0.f);
    ushort h = f2bf(un);
    Uh[rb + k] = h;
    Ul[rb + k] = f2bf(un - bf2f(h));
  }
}

// ---------------- ln2k: Vn = LN2(V_raw) -> bf16 hi/lo [rowsPad][800] ----------------
__global__ __launch_bounds__(256) void ln2k(const float* __restrict__ Vr,
                                            const float* __restrict__ gn,
                                            const float* __restrict__ bn,
                                            ushort* __restrict__ Vh,
                                            ushort* __restrict__ Vl) {
  int r = blockIdx.x * 4 + (threadIdx.x >> 6);
  int lane = threadIdx.x & 63;
  const float* row = Vr + (size_t)r * EMB;
  float x[13];
  float s1 = 0.f, s2 = 0.f;
  #pragma unroll
  for (int i = 0; i < 13; ++i) {
    int k = lane + 64 * i;
    float v = (k < EMB) ? row[k] : 0.f;
    x[i] = v; s1 += v; s2 += v * v;
  }
  #pragma unroll
  for (int m = 1; m < 64; m <<= 1) { s1 += __shfl_xor(s1, m); s2 += __shfl_xor(s2, m); }
  float mu = s1 * (1.f / EMB);
  float rstd = rsqrtf(s2 * (1.f / EMB) - mu * mu + 1e-5f);
  size_t rb = (size_t)r * EMB;
  #pragma unroll
  for (int i = 0; i < 13; ++i) {
    int k = lane + 64 * i;
    if (k < EMB) {
      float v = (x[i] - mu) * rstd * gn[k] + bn[k];
      ushort h = f2bf(v);
      Vh[rb + k] = h;
      Vl[rb + k] = f2bf(v - bf2f(h));
    }
  }
}

// ---------------- universal bf16 hi/lo 3-product MFMA GEMM ----------------
// C[m][n] = sum_k A[m][k]*B[n][k] (+ A2[m][k]*B2[n][k]) (+bias) (relu?)
// A,B row-major K-contiguous hi/lo pairs. 128x128 tile, BK=32, 4 waves.
template <bool HAS2, bool HASBIAS, bool RELU>
__global__ __launch_bounds__(256, 3) void gemm_mf(
    const ushort* __restrict__ Ah, const ushort* __restrict__ Al, int lda,
    const ushort* __restrict__ Bh, const ushort* __restrict__ Bl, int ldb,
    const ushort* __restrict__ A2h, const ushort* __restrict__ A2l, int lda2,
    const ushort* __restrict__ B2h, const ushort* __restrict__ B2l, int ldb2,
    const float* __restrict__ bias, float* __restrict__ C, size_t ldc,
    int K, int Mvalid, int nvalid, int ncol0) {
  __shared__ ushort smem[16384];  // 4 x [128][32] bf16 tiles, 32 KB
  const int tid = threadIdx.x, lane = tid & 63, wid = tid >> 6;
  const int wm = wid >> 1, wn = wid & 1;
  const int n0b = blockIdx.x * 128, m0 = blockIdx.y * 128;
  const int lr = lane & 15, lk = lane >> 4;

  f32x4 acc[4][4];
  #pragma unroll
  for (int i = 0; i < 4; ++i)
    #pragma unroll
    for (int j = 0; j < 4; ++j) acc[i][j] = (f32x4){0.f, 0.f, 0.f, 0.f};

  const int srow = lane >> 2;
  const int scol = (lane & 3) * 8;
  const int npass = HAS2 ? 2 : 1;

  for (int pass = 0; pass < npass; ++pass) {
    const ushort* pAh = (HAS2 && pass) ? A2h : Ah;
    const ushort* pAl = (HAS2 && pass) ? A2l : Al;
    const ushort* pBh = (HAS2 && pass) ? B2h : Bh;
    const ushort* pBl = (HAS2 && pass) ? B2l : Bl;
    const int plda = (HAS2 && pass) ? lda2 : lda;
    const int pldb = (HAS2 && pass) ? ldb2 : ldb;

    for (int k0 = 0; k0 < K; k0 += 32) {
      __syncthreads();
      #pragma unroll
      for (int j = 0; j < 8; ++j) {
        int t = wid + 4 * j;
        int buf = t >> 3, i = t & 7;
        const ushort* g;
        int ld_, r0;
        if (buf == 0)      { g = pAh; ld_ = plda; r0 = m0; }
        else if (buf == 1) { g = pAl; ld_ = plda; r0 = m0; }
        else if (buf == 2) { g = pBh; ld_ = pldb; r0 = n0b; }
        else               { g = pBl; ld_ = pldb; r0 = n0b; }
        const ushort* src = g + (size_t)(r0 + i * 16 + srow) * ld_ + k0 + scol;
        async_copy16(smem + buf * 4096 + i * 512, src);
      }
      __syncthreads();

      short8v ah[4], al[4], bh[4], bl[4];
      #pragma unroll
      for (int f = 0; f < 4; ++f) {
        ah[f] = *(const short8v*)&smem[0     + (wm * 64 + f * 16 + lr) * 32 + lk * 8];
        al[f] = *(const short8v*)&smem[4096  + (wm * 64 + f * 16 + lr) * 32 + lk * 8];
        bh[f] = *(const short8v*)&smem[8192  + (wn * 64 + f * 16 + lr) * 32 + lk * 8];
        bl[f] = *(const short8v*)&smem[12288 + (wn * 64 + f * 16 + lr) * 32 + lk * 8];
      }
      #pragma unroll
      for (int mi = 0; mi < 4; ++mi)
        #pragma unroll
        for (int ni = 0; ni < 4; ++ni) {
          acc[mi][ni] = __builtin_amdgcn_mfma_f32_16x16x32_bf16(ah[mi], bh[ni], acc[mi][ni], 0, 0, 0);
          acc[mi][ni] = __builtin_amdgcn_mfma_f32_16x16x32_bf16(al[mi], bh[ni], acc[mi][ni], 0, 0, 0);
          acc[mi][ni] = __builtin_amdgcn_mfma_f32_16x16x32_bf16(ah[mi], bl[ni], acc[mi][ni], 0, 0, 0);
        }
    }
  }

  // epilogue: C/D layout col=lane&15, row=(lane>>4)*4+reg  [m89-verified]
  #pragma unroll
  for (int mi = 0; mi < 4; ++mi)
    #pragma unroll
    for (int ni = 0; ni < 4; ++ni) {
      #pragma unroll
      for (int r = 0; r < 4; ++r) {
        int m = m0 + wm * 64 + mi * 16 + lk * 4 + r;
        int n = n0b + wn * 64 + ni * 16 + lr;
        if (m < Mvalid && n < nvalid) {
          float v = acc[mi][ni][r];
          if (HASBIAS) v += bias[n];
          if (RELU) v = fmaxf(v, 0.f);
          C[(size_t)m * ldc + ncol0 + n] = v;
        }
      }
    }
}

// ---------------- launch ----------------
extern "C" void kernel_launch(void* const* d_in, const int* in_sizes, int n_in,
                              void* d_out, int out_size, void* d_ws, size_t ws_size,
                              hipStream_t stream) {
  const float* img = (const float*)d_in[0];
  const float* node_feats = (const float*)d_in[1];
  const int* ei = (const int*)d_in[2];
  const float* s1_Wl = (const float*)d_in[3];
  const float* s1_bl = (const float*)d_in[4];
  const float* s1_Wr = (const float*)d_in[5];
  const float* s2_Wl = (const float*)d_in[6];
  const float* s2_bl = (const float*)d_in[7];
  const float* s2_Wr = (const float*)d_in[8];
  const float* i_W1 = (const float*)d_in[9];
  const float* i_b1 = (const float*)d_in[10];
  const float* i_g1 = (const float*)d_in[11];
  const float* i_be1 = (const float*)d_in[12];
  const float* i_W2 = (const float*)d_in[13];
  const float* i_b2 = (const float*)d_in[14];
  const float* i_g2 = (const float*)d_in[15];
  const float* i_be2 = (const float*)d_in[16];
  const float* i_W3 = (const float*)d_in[17];
  const float* i_b3 = (const float*)d_in[18];
  const float* i_gn = (const float*)d_in[19];
  const float* i_bn = (const float*)d_in[20];
  const float* p_W1 = (const float*)d_in[21];
  const float* p_b1 = (const float*)d_in[22];
  const float* p_g1 = (const float*)d_in[23];
  const float* p_be1 = (const float*)d_in[24];
  const float* p_W2 = (const float*)d_in[25];
  const float* p_b2 = (const float*)d_in[26];
  const float* p_gn = (const float*)d_in[27];
  const float* p_bn = (const float*)d_in[28];

  const int E = in_sizes[2] / 2;

  // -------- workspace layout --------
  char* base = (char*)d_ws;
  size_t off = 0;
  auto alloc = [&](size_t bytes) -> void* {
    void* p = base + off;
    off = (off + bytes + 255) & ~(size_t)255;
    return p;
  };
  // f32 intermediates
  float* mean1 = (float*)alloc(700 * 512 * 4);
  float* h     = (float*)alloc(700 * 2048 * 4);
  float* mean2 = (float*)alloc(700 * 2048 * 4);
  float* t1    = (float*)alloc(256 * 800 * 4);
  float* t2    = (float*)alloc(256 * 1000 * 4);
  float* t3    = (float*)alloc(256 * 800 * 4);
  float* B1    = (float*)alloc(200 * 1000 * 4);
  float* O1    = (float*)alloc(500 * 1000 * 4);
  // split activations (hi/lo bf16)
  ushort* nfh = (ushort*)alloc(768 * 512 * 2);
  ushort* nfl = (ushort*)alloc(768 * 512 * 2);
  ushort* m1h = (ushort*)alloc(768 * 512 * 2);
  ushort* m1l = (ushort*)alloc(768 * 512 * 2);
  ushort* hh  = (ushort*)alloc(768 * 2048 * 2);
  ushort* hl  = (ushort*)alloc(768 * 2048 * 2);
  ushort* m2h = (ushort*)alloc(768 * 2048 * 2);
  ushort* m2l = (ushort*)alloc(768 * 2048 * 2);
  ushort* ndh = (ushort*)alloc(768 * 512 * 2);
  ushort* ndl = (ushort*)alloc(768 * 512 * 2);
  ushort* xih = (ushort*)alloc(256 * 512 * 2);
  ushort* xil = (ushort*)alloc(256 * 512 * 2);
  ushort* t1h = (ushort*)alloc(256 * 800 * 2);
  ushort* t1l = (ushort*)alloc(256 * 800 * 2);
  ushort* t2h = (ushort*)alloc(256 * 1024 * 2);
  ushort* t2l = (ushort*)alloc(256 * 1024 * 2);
  ushort* imgh = (ushort*)alloc(256 * 800 * 2);
  ushort* imgl = (ushort*)alloc(256 * 800 * 2);
  // transposed split weights [Npad][Kpad]
  ushort* w1lh = (ushort*)alloc((size_t)2048 * 512 * 2);
  ushort* w1ll = (ushort*)alloc((size_t)2048 * 512 * 2);
  ushort* w1rh = (ushort*)alloc((size_t)2048 * 512 * 2);
  ushort* w1rl = (ushort*)alloc((size_t)2048 * 512 * 2);
  ushort* w2lh = (ushort*)alloc((size_t)512 * 2048 * 2);
  ushort* w2ll = (ushort*)alloc((size_t)512 * 2048 * 2);
  ushort* w2rh = (ushort*)alloc((size_t)512 * 2048 * 2);
  ushort* w2rl = (ushort*)alloc((size_t)512 * 2048 * 2);
  ushort* iw1h = (ushort*)alloc((size_t)896 * 512 * 2);
  ushort* iw1l = (ushort*)alloc((size_t)896 * 512 * 2);
  ushort* iw2h = (ushort*)alloc((size_t)1024 * 800 * 2);
  ushort* iw2l = (ushort*)alloc((size_t)1024 * 800 * 2);
  ushort* iw3h = (ushort*)alloc((size_t)896 * 1024 * 2);
  ushort* iw3l = (ushort*)alloc((size_t)896 * 1024 * 2);
  ushort* pw1ah = (ushort*)alloc((size_t)1024 * 512 * 2);
  ushort* pw1al = (ushort*)alloc((size_t)1024 * 512 * 2);
  ushort* pw1bh = (ushort*)alloc((size_t)1024 * 512 * 2);
  ushort* pw1bl = (ushort*)alloc((size_t)1024 * 512 * 2);
  ushort* W2Th = (ushort*)alloc((size_t)896 * 1024 * 2);
  ushort* W2Tl = (ushort*)alloc((size_t)896 * 1024 * 2);
  int* cnt       = (int*)alloc(704 * 4);
  int* row_start = (int*)alloc(704 * 4);
  int* pos       = (int*)alloc(704 * 4);
  int* srcs      = (int*)alloc(50176 * 4);

  // chunked pair-branch buffers: per row 1024*2*2 (U) + 800*4 (Vraw) + 800*2*2 (Vn)
  size_t avail = (ws_size > off + (4u << 20)) ? ws_size - off - (4u << 20) : 0;
  long maxRows = (long)(avail / 10496) - 128;
  int CA = (int)(maxRows / 500);
  if (CA < 1) CA = 1;
  if (CA > 50) CA = 50;
  int nch = (NATTRS + CA - 1) / CA;
  int rowsPadAlloc = ((CA * 500 + 127) / 128) * 128;
  ushort* Uh   = (ushort*)alloc((size_t)rowsPadAlloc * 1024 * 2);
  ushort* Ul   = (ushort*)alloc((size_t)rowsPadAlloc * 1024 * 2);
  float*  Vraw = (float*) alloc((size_t)rowsPadAlloc * 800 * 4);
  ushort* Vh   = (ushort*)alloc((size_t)rowsPadAlloc * 800 * 2);
  ushort* Vl   = (ushort*)alloc((size_t)rowsPadAlloc * 800 * 2);

  float* pairp = (float*)d_out;
  float* nodes = (float*)d_out + (size_t)BB * NPAIR;

  const ushort* NU = nullptr;

  // -------- CSR build --------
  hipMemsetAsync(cnt, 0, NNODE * sizeof(int), stream);
  k_count<<<(E + 255) / 256, 256, 0, stream>>>(ei, cnt, E);
  k_scan<<<1, 1024, 0, stream>>>(cnt, row_start, pos);
  k_fill<<<(E + 255) / 256, 256, 0, stream>>>(ei, pos, srcs, E);

  // -------- weight prep (transpose + hi/lo split) --------
  prep_wT<<<dim3(2048 / 32, 512 / 32), 256, 0, stream>>>(s1_Wl, w1lh, w1ll, 512, 2048, 512);
  prep_wT<<<dim3(2048 / 32, 512 / 32), 256, 0, stream>>>(s1_Wr, w1rh, w1rl, 512, 2048, 512);
  prep_wT<<<dim3(512 / 32, 2048 / 32), 256, 0, stream>>>(s2_Wl, w2lh, w2ll, 2048, 512, 2048);
  prep_wT<<<dim3(512 / 32, 2048 / 32), 256, 0, stream>>>(s2_Wr, w2rh, w2rl, 2048, 512, 2048);
  prep_wT<<<dim3(896 / 32, 512 / 32), 256, 0, stream>>>(i_W1, iw1h, iw1l, 512, 800, 512);
  prep_wT<<<dim3(1024 / 32, 800 / 32), 256, 0, stream>>>(i_W2, iw2h, iw2l, 800, 1000, 800);
  prep_wT<<<dim3(896 / 32, 1024 / 32), 256, 0, stream>>>(i_W3, iw3h, iw3l, 1000, 800, 1024);
  prep_wT<<<dim3(1024 / 32, 512 / 32), 256, 0, stream>>>(p_W1, pw1ah, pw1al, 512, 1000, 512);
  prep_wT<<<dim3(1024 / 32, 512 / 32), 256, 0, stream>>>(p_W1 + 512 * 1000, pw1bh, pw1bl, 512, 1000, 512);
  prep_wT<<<dim3(896 / 32, 1024 / 32), 256, 0, stream>>>(p_W2, W2Th, W2Tl, 1000, 800, 1024);

  // -------- SAGE layer 1 --------
  agg_mean<<<dim3(NNODE, IN_F / 256), 256, 0, stream>>>(node_feats, srcs, row_start, mean1, IN_F);
  split_f32<<<512, 256, 0, stream>>>(node_feats, nfh, nfl, 700, 512, 512, 768L * 512);
  split_f32<<<512, 256, 0, stream>>>(mean1, m1h, m1l, 700, 512, 512, 768L * 512);
  gemm_mf<true, true, true><<<dim3(16, 6), 256, 0, stream>>>(
      m1h, m1l, 512, w1lh, w1ll, 512, nfh, nfl, 512, w1rh, w1rl, 512,
      s1_bl, h, 2048, 512, 700, 2048, 0);

  // -------- SAGE layer 2 --------
  agg_mean<<<dim3(NNODE, HID / 256), 256, 0, stream>>>(h, srcs, row_start, mean2, HID);
  split_f32<<<1024, 256, 0, stream>>>(h, hh, hl, 700, 2048, 2048, 768L * 2048);
  split_f32<<<1024, 256, 0, stream>>>(mean2, m2h, m2l, 700, 2048, 2048, 768L * 2048);
  gemm_mf<true, true, false><<<dim3(4, 6), 256, 0, stream>>>(
      m2h, m2l, 2048, w2lh, w2ll, 2048, hh, hl, 2048, w2rh, w2rl, 2048,
      s2_bl, nodes, 512, 2048, 700, 512, 0);

  // -------- image branch --------
  split_f32<<<256, 256, 0, stream>>>(img, xih, xil, 256, 512, 512, 256L * 512);
  gemm_mf<false, true, false><<<dim3(7, 2), 256, 0, stream>>>(
      xih, xil, 512, iw1h, iw1l, 512, NU, NU, 0, NU, NU, 0,
      i_b1, t1, 800, 512, 256, 800, 0);
  ln_rows<true><<<BB, 256, 0, stream>>>(t1, i_g1, i_be1, 800);
  split_f32<<<256, 256, 0, stream>>>(t1, t1h, t1l, 256, 800, 800, 256L * 800);
  gemm_mf<false, true, false><<<dim3(8, 2), 256, 0, stream>>>(
      t1h, t1l, 800, iw2h, iw2l, 800, NU, NU, 0, NU, NU, 0,
      i_b2, t2, 1000, 800, 256, 1000, 0);
  ln_rows<true><<<BB, 256, 0, stream>>>(t2, i_g2, i_be2, 1000);
  split_f32<<<256, 256, 0, stream>>>(t2, t2h, t2l, 256, 1000, 1024, 256L * 1024);
  gemm_mf<false, true, false><<<dim3(7, 2), 256, 0, stream>>>(
      t2h, t2l, 1024, iw3h, iw3l, 1024, NU, NU, 0, NU, NU, 0,
      i_b3, t3, 800, 1024, 256, 800, 0);
  ln_rows<false><<<BB, 256, 0, stream>>>(t3, i_gn, i_bn, EMB);
  prep_img<<<BB, 256, 0, stream>>>(t3, imgh, imgl);

  // -------- pair-branch prep: B1 / O1 --------
  split_f32<<<512, 256, 0, stream>>>(nodes, ndh, ndl, 700, 512, 512, 768L * 512);
  gemm_mf<false, true, false><<<dim3(8, 2), 256, 0, stream>>>(
      ndh, ndl, 512, pw1ah, pw1al, 512, NU, NU, 0, NU, NU, 0,
      p_b1, B1, 1000, 512, 200, 1000, 0);
  gemm_mf<false, false, false><<<dim3(8, 4), 256, 0, stream>>>(
      ndh + 200 * 512, ndl + 200 * 512, 512, pw1bh, pw1bl, 512, NU, NU, 0, NU, NU, 0,
      nullptr, O1, 1000, 512, 500, 1000, 0);

  // -------- chunked pair branch --------
  for (int c = 0; c < nch; ++c) {
    int a0 = c * CA;
    int ca = (NATTRS - a0 < CA) ? (NATTRS - a0) : CA;
    int rows = ca * 500;
    int rowsPad = ((rows + 127) / 128) * 128;
    int p0 = a0 * 500;

    ugen<<<rowsPad / 4, 256, 0, stream>>>(B1, O1, p_g1, p_be1, Uh, Ul, p0);
    gemm_mf<false, true, false><<<dim3(7, rowsPad / 128), 256, 0, stream>>>(
        Uh, Ul, 1024, W2Th, W2Tl, 1024, NU, NU, 0, NU, NU, 0,
        p_b2, Vraw, 800, 1024, rowsPad, 800, 0);
    ln2k<<<rowsPad / 4, 256, 0, stream>>>(Vraw, p_gn, p_bn, Vh, Vl);
    gemm_mf<false, false, false><<<dim3(rowsPad / 128, 2), 256, 0, stream>>>(
        imgh, imgl, 800, Vh, Vl, 800, NU, NU, 0, NU, NU, 0,
        nullptr, pairp, NPAIR, 800, 256, rows, p0);
  }
}